// Round 11
// baseline (1109.374 us; speedup 1.0000x reference)
//
#include <hip/hip_runtime.h>
#include <hip/hip_bf16.h>

// DIAGNOSTIC ROUND (R10 resubmit): R9 kernel with the store loop executed 3x
// (idempotent — identical values to identical addresses each pass; the
// asm memory clobber between passes prevents dead-store elimination).
// Purpose: make our dispatch the LONGEST (~815 us > ~540 us fills) so its
// rocprof counter row surfaces in the top-5, exposing FETCH_SIZE/WRITE_SIZE
// for OUR store stream. Discriminates:
//   H1 write-allocate fetch (FETCH ~= WRITE ~= 2.4 GiB, hbm ~6.2 TB/s)
//   H2 incompressible-write ceiling ~3.1 TB/s (FETCH ~= 0, hbm ~3.1)
//   H3 hidden overhead (FETCH ~= 0, dur ~405 us, hbm ~6.2)

constexpr int F   = 1024;
constexpr int T   = 100;
constexpr int F4  = F / 4;   // 256 float4s per row
constexpr int RPB = 8;       // batch rows per block

typedef float v4f __attribute__((ext_vector_type(4)));

__global__ __launch_bounds__(256) void TemporalSpikeCoder_78125455114738_kernel(
    const float* __restrict__ x, float* __restrict__ out) {
    const int b0 = blockIdx.x * RPB;       // first batch row of this block
    const int f4 = threadIdx.x;            // float4 index within row

    const v4f* __restrict__ x4 = reinterpret_cast<const v4f*>(x);
    v4f* __restrict__ o4 = reinterpret_cast<v4f*>(out);

    // Load this thread's 8 x-float4s once, convert to spike times.
    int sx[RPB], sy[RPB], sz[RPB], sw[RPB];
    #pragma unroll
    for (int r = 0; r < RPB; ++r) {
        const v4f xv = x4[(b0 + r) * F4 + f4];
        sx[r] = (int)((1.0f - xv.x) * 100.0f);
        sy[r] = (int)((1.0f - xv.y) * 100.0f);
        sz[r] = (int)((1.0f - xv.z) * 100.0f);
        sw[r] = (int)((1.0f - xv.w) * 100.0f);
    }

    v4f* o = o4 + (size_t)b0 * (T * F4) + f4;
    for (int j = 0; j < 3; ++j) {          // 3x idempotent passes (diagnostic)
        asm volatile("" ::: "memory");     // block DSE / cross-pass merging
        for (int t = 0; t < T; ++t) {
            #pragma unroll
            for (int r = 0; r < RPB; ++r) {
                v4f v;
                v.x = (sx[r] == t) ? 1.0f : 0.0f;
                v.y = (sy[r] == t) ? 1.0f : 0.0f;
                v.z = (sz[r] == t) ? 1.0f : 0.0f;
                v.w = (sw[r] == t) ? 1.0f : 0.0f;
                o[(size_t)r * (T * F4) + (size_t)t * F4] = v;
            }
        }
    }
}

extern "C" void kernel_launch(void* const* d_in, const int* in_sizes, int n_in,
                              void* d_out, int out_size, void* d_ws, size_t ws_size,
                              hipStream_t stream) {
    const float* x = (const float*)d_in[0];
    float* out = (float*)d_out;
    const int B = in_sizes[0] / F;              // 2048
    const int grid = B / RPB;                   // 256 blocks = 1 per CU
    TemporalSpikeCoder_78125455114738_kernel<<<grid, 256, 0, stream>>>(x, out);
}